// Round 8
// baseline (2737.241 us; speedup 1.0000x reference)
//
#include <hip/hip_runtime.h>

#define M_TOK 8192
#define N_OUT 4096
#define K_IN  4096
#define BK    64
#define NT    (K_IN / BK)   // 64 k-tiles

typedef __bf16 bf16;
typedef bf16  bf16x4  __attribute__((ext_vector_type(4)));
typedef bf16  bf16x8  __attribute__((ext_vector_type(8)));
typedef float floatx4 __attribute__((ext_vector_type(4)));

__device__ __forceinline__ bf16 dec_code(int c, float s) {
    // clip(c-3, -3, 3) == min(c,6)-3 for c in 0..7
    int q = (c > 6 ? 6 : c) - 3;
    return (bf16)((float)q * s);
}

__device__ __forceinline__ void async_ld16(const bf16* g, const bf16* l) {
    __builtin_amdgcn_global_load_lds(
        (const __attribute__((address_space(1))) void*)g,
        (__attribute__((address_space(3))) void*)l,
        16, 0, 0);
}

// ---------------------------------------------------------------------------
// Phase 1 (merged): dequantize W -> bf16 [N][K]  AND  convert x fp32 -> bf16
//   blocks [0, 2048)          : dequant (2 threads per 64-elem group)
//   blocks [2048, 2048+16384) : x conversion (8 elems / thread)
// ---------------------------------------------------------------------------
__global__ __launch_bounds__(256)
void prep_kernel(const int* __restrict__ wq, const float* __restrict__ wscale,
                 const float* __restrict__ x,
                 bf16* __restrict__ W, bf16* __restrict__ xb)
{
    const int b = blockIdx.x;
    const int t = threadIdx.x;
    if (b < 2048) {
        int idx  = b * 256 + t;              // 0 .. 2*NUM_GROUPS-1
        int g    = idx >> 1;
        int half = idx & 1;
        const int* wp = wq + (size_t)g * 24 + half * 12;
        int4 r0 = *(const int4*)(wp);
        int4 r1 = *(const int4*)(wp + 4);
        int4 r2 = *(const int4*)(wp + 8);
        float s = wscale[g];
        int by[12] = { r0.x, r0.y, r0.z, r0.w, r1.x, r1.y, r1.z, r1.w,
                       r2.x, r2.y, r2.z, r2.w };
        bf16* dst = W + (size_t)g * 64 + half * 32;
#pragma unroll
        for (int tri = 0; tri < 4; ++tri) {
            int b0 = by[tri * 3 + 0];
            int b1 = by[tri * 3 + 1];
            int b2 = by[tri * 3 + 2];
            bf16x8 h;
            h[0] = dec_code(b0 & 7, s);
            h[1] = dec_code((b0 >> 3) & 7, s);
            h[2] = dec_code(((b0 >> 6) & 3) | ((b1 & 1) << 2), s);
            h[3] = dec_code((b1 >> 1) & 7, s);
            h[4] = dec_code((b1 >> 4) & 7, s);
            h[5] = dec_code(((b1 >> 7) & 1) | ((b2 & 3) << 1), s);
            h[6] = dec_code((b2 >> 2) & 7, s);
            h[7] = dec_code((b2 >> 5) & 7, s);
            *(bf16x8*)(dst + tri * 8) = h;
        }
    } else {
        size_t i = ((size_t)(b - 2048) * 256 + t) * 8;
        float4 a = *(const float4*)(x + i);
        float4 c = *(const float4*)(x + i + 4);
        bf16x8 h = { (bf16)a.x, (bf16)a.y, (bf16)a.z, (bf16)a.w,
                     (bf16)c.x, (bf16)c.y, (bf16)c.z, (bf16)c.w };
        *(bf16x8*)(xb + i) = h;
    }
}

// ---------------------------------------------------------------------------
// Phase 2: bf16 B^T GEMM, 256x256 tile, BK=64, 8 waves (2M x 4N), 512 thr.
//   Round-3's 4-phase schedule + counted vmcnt, but SINGLE-buffered LDS with
//   in-place region staging -> 64 KiB LDS -> 2 blocks/CU (4 waves/SIMD).
//   Natural block mapping (round-5 measured: XCD override costs ~15%).
//
// Region liveness inside a tile (the key to single-buffer correctness):
//   P0 ds-reads: A rows wm*128+0..63  (wm0->AQ0, wm1->AQ2) + B nj0
//   P1 ds-reads: B nj1                (=> ALL of B dead after P1; frags in regs)
//   P2 ds-reads: A rows wm*128+64..127 (wm0->AQ1, wm1->AQ3)
//   P3 ds-reads: none
//   => AQ0,AQ2 dead after P0; B dead after P1; AQ1,AQ3 dead after P2.
// Each wave's PH_SYNC lgkmcnt(0) completes its ds-reads BEFORE it reaches the
// phase-end barrier, so a region staged after that barrier cannot race reads.
//
// Stage plan for tile kt+1 (into the SAME buffer, after the region dies):
//   P1: AQ0,AQ2      P2: BQ0,BQ1,BQ2,BQ3      P3: AQ1,AQ3
// Per-wave FIFO trace (steady; entering tile t outstanding = [AQ1,AQ3](t)):
//   P1 issues 2 -> 4;  P1-end: vmcnt(2) retires AQ1,AQ3(t) (lead 2 ph; read P2)
//   P2 issues 4 -> 6;  P3 issues 2 -> 8
//   P3-end: vmcnt(2) retires AQ0,AQ2,BQ0-3 of t+1 (leads 2-3 ph; read next P0),
//           leaving [AQ1,AQ3](t+1) -> invariant.
// Last tile: P1-end vmcnt(0); P3-end no wait. Never drains in steady state.
// ---------------------------------------------------------------------------
__global__ __launch_bounds__(512, 4)
void gemm_kernel(const bf16* __restrict__ A, const bf16* __restrict__ B,
                 const float* __restrict__ bias, float* __restrict__ out)
{
    __shared__ bf16 As[256][BK];   // 32 KiB
    __shared__ bf16 Bs[256][BK];   // 32 KiB   (64 KiB total -> 2 blocks/CU)

    const int t     = threadIdx.x;
    const int nBase = blockIdx.x * 256;
    const int mBase = blockIdx.y * 256;

    const int wave = t >> 6;
    const int lane = t & 63;
    const int quad = lane >> 4;
    const int r16  = lane & 15;
    const int wm   = wave >> 2;      // 0..1  (M dim)
    const int wn   = wave & 3;       // 0..3  (N dim)
    const int sw   = r16 & 7;

    // staging: thread t covers row (t>>3) of a 64-row block, physical 16B
    // chunk (t&7); fetches logical chunk (t&7)^(row&7) so a linear
    // global_load_lds write produces the swizzled layout.
    const int rowInBlk = t >> 3;                  // 0..63
    const int lc       = (t & 7) ^ (rowInBlk & 7);

    const bf16* aSrc = A + (size_t)(mBase + rowInBlk) * K_IN + lc * 8;
    const bf16* bSrc = B + (size_t)(nBase + rowInBlk) * K_IN + lc * 8;
    bf16* aLds0 = &As[0][0] + t * 8;              // + rowOff*64
    bf16* bLds0 = &Bs[0][0] + t * 8;

#define STAGE_A(KT1, ROFF) \
    async_ld16(aSrc + (size_t)(ROFF) * K_IN + (size_t)(KT1) * BK, \
               aLds0 + (ROFF) * BK)
#define STAGE_B(KT1, ROFF) \
    async_ld16(bSrc + (size_t)(ROFF) * K_IN + (size_t)(KT1) * BK, \
               bLds0 + (ROFF) * BK)

    floatx4 acc[8][4];
#pragma unroll
    for (int i = 0; i < 8; ++i)
#pragma unroll
        for (int j = 0; j < 4; ++j)
            acc[i][j] = (floatx4){0.f, 0.f, 0.f, 0.f};

    bf16x8 afr[2][4];   // A frags for current m-half
    bf16x8 bfr[2][4];   // B frags for whole tile (nj0 loaded P0, nj1 P1)

#define LOAD_A(MH) do {                                                         \
        _Pragma("unroll") for (int ks = 0; ks < 2; ++ks)                        \
        _Pragma("unroll") for (int q = 0; q < 4; ++q)                           \
            afr[ks][q] = *(const bf16x8*)(                                      \
                &As[wm * 128 + ((MH) * 4 + q) * 16 + r16]                       \
                   [((ks * 4 + quad) ^ sw) * 8]);                               \
    } while (0)
#define LOAD_B(NJ) do {                                                         \
        _Pragma("unroll") for (int ks = 0; ks < 2; ++ks)                        \
        _Pragma("unroll") for (int j = 0; j < 2; ++j)                           \
            bfr[ks][(NJ) * 2 + j] = *(const bf16x8*)(                           \
                &Bs[wn * 64 + ((NJ) * 2 + j) * 16 + r16]                        \
                   [((ks * 4 + quad) ^ sw) * 8]);                               \
    } while (0)

#define CLUSTER(MOFF, NOFF) do {                                                \
        __builtin_amdgcn_s_setprio(1);                                          \
        _Pragma("unroll") for (int ks = 0; ks < 2; ++ks)                        \
        _Pragma("unroll") for (int q = 0; q < 4; ++q)                           \
        _Pragma("unroll") for (int j = 0; j < 2; ++j)                           \
            acc[(MOFF) + q][(NOFF) + j] =                                       \
                __builtin_amdgcn_mfma_f32_16x16x32_bf16(                        \
                    afr[ks][q], bfr[ks][(NOFF) + j],                            \
                    acc[(MOFF) + q][(NOFF) + j], 0, 0, 0);                      \
        __builtin_amdgcn_s_setprio(0);                                          \
    } while (0)

#define PH_SYNC() do {                                                          \
        asm volatile("s_barrier\n\ts_waitcnt lgkmcnt(0)" ::: "memory");         \
        __builtin_amdgcn_sched_barrier(0);                                      \
    } while (0)
#define PH_END() asm volatile("s_barrier" ::: "memory")

    // ---- prologue: tile 0; FIFO order [BQ0..BQ3, AQ0, AQ2, AQ1, AQ3] ----
    STAGE_B(0, 0);   STAGE_B(0, 64);  STAGE_B(0, 128); STAGE_B(0, 192);
    STAGE_A(0, 0);   STAGE_A(0, 128); STAGE_A(0, 64);  STAGE_A(0, 192);
    asm volatile("s_waitcnt vmcnt(2)" ::: "memory");   // retire all but AQ1,AQ3
    asm volatile("s_barrier" ::: "memory");

    for (int kt = 0; kt < NT; ++kt) {
        const bool hn = (kt + 1 < NT);

        // ---- P0: ds A(mh0)+B(nj0); no stages (regions still live) ----
        LOAD_A(0);
        LOAD_B(0);
        PH_SYNC();
        CLUSTER(0, 0);
        PH_END();

        // ---- P1: ds B(nj1); stage AQ0,AQ2 of kt+1 (AQ0/AQ2 died at P0-end)
        LOAD_B(1);
        if (hn) { STAGE_A(kt + 1, 0); STAGE_A(kt + 1, 128); }
        PH_SYNC();
        CLUSTER(0, 2);
        if (hn) asm volatile("s_waitcnt vmcnt(2)" ::: "memory");
        else    asm volatile("s_waitcnt vmcnt(0)" ::: "memory");
        PH_END();   // AQ1,AQ3 of tile kt now LDS-visible for P2

        // ---- P2: ds A(mh1); stage B of kt+1 (B died at P1-end) ----
        LOAD_A(1);
        if (hn) {
            STAGE_B(kt + 1, 0);   STAGE_B(kt + 1, 64);
            STAGE_B(kt + 1, 128); STAGE_B(kt + 1, 192);
        }
        PH_SYNC();
        CLUSTER(4, 0);
        PH_END();

        // ---- P3: stage AQ1,AQ3 of kt+1 (AQ1/AQ3 died at P2-end) ----
        if (hn) { STAGE_A(kt + 1, 64); STAGE_A(kt + 1, 192); }
        PH_SYNC();
        CLUSTER(4, 2);
        if (hn) asm volatile("s_waitcnt vmcnt(2)" ::: "memory");
        PH_END();   // next P0's ds_reads safe: BQ*,AQ0,AQ2 of kt+1 landed
    }

#undef PH_END
#undef PH_SYNC
#undef CLUSTER
#undef LOAD_B
#undef LOAD_A
#undef STAGE_A
#undef STAGE_B

    const int colBase = nBase + wn * 64;
#pragma unroll
    for (int ni = 0; ni < 4; ++ni) {
        int col  = colBase + ni * 16 + r16;
        float bv = bias[col];
#pragma unroll
        for (int mi = 0; mi < 8; ++mi) {
            int row0 = mBase + wm * 128 + mi * 16 + quad * 4;
#pragma unroll
            for (int r = 0; r < 4; ++r)
                out[(size_t)(row0 + r) * N_OUT + col] = acc[mi][ni][r] + bv;
        }
    }
}

// ---------------------------------------------------------------------------
// Fallback: proven fused kernel (round-1, passed) if ws is too small
// ---------------------------------------------------------------------------
__global__ __launch_bounds__(256, 2)
void linear3bit_fused(const float* __restrict__ x,
                      const int*   __restrict__ wq,
                      const float* __restrict__ wscale,
                      const float* __restrict__ bias,
                      float*       __restrict__ out)
{
    __shared__ bf16 As[128][BK];
    __shared__ bf16 Bs[128][BK];

    const int t     = threadIdx.x;
    const int mBase = blockIdx.y * 128;
    const int nBase = blockIdx.x * 128;

    const int wave = t >> 6;
    const int lane = t & 63;
    const int quad = lane >> 4;
    const int r16  = lane & 15;
    const int wm   = wave & 1;
    const int wn   = wave >> 1;

    floatx4 acc[4][4];
#pragma unroll
    for (int i = 0; i < 4; ++i)
#pragma unroll
        for (int j = 0; j < 4; ++j)
            acc[i][j] = (floatx4){0.f, 0.f, 0.f, 0.f};

    const int gl   = t >> 1;
    const int half = t & 1;
    const float* xBase = x + (size_t)mBase * K_IN;

    float4 aReg[8];
    int4   bReg[3];
    float  sReg;

    auto loadTile = [&](int kt) {
#pragma unroll
        for (int i = 0; i < 8; ++i) {
            int linear = i * 256 + t;
            int row    = linear >> 4;
            int c4     = (linear & 15) << 2;
            aReg[i] = *(const float4*)(xBase + (size_t)row * K_IN + kt * BK + c4);
        }
        size_t g = (size_t)(nBase + gl) * 64 + kt;
        const int* wp = wq + g * 24 + half * 12;
        bReg[0] = *(const int4*)(wp);
        bReg[1] = *(const int4*)(wp + 4);
        bReg[2] = *(const int4*)(wp + 8);
        sReg = wscale[g];
    };

    auto stage = [&]() {
#pragma unroll
        for (int i = 0; i < 8; ++i) {
            int linear = i * 256 + t;
            int row    = linear >> 4;
            int c4     = (linear & 15) << 2;
            float4 v = aReg[i];
            bf16x4 h = { (bf16)v.x, (bf16)v.y, (bf16)v.z, (bf16)v.w };
            *(bf16x4*)(&As[row][c4]) = h;
        }
        const float s = sReg;
        int by[12] = { bReg[0].x, bReg[0].y, bReg[0].z, bReg[0].w,
                       bReg[1].x, bReg[1].y, bReg[1].z, bReg[1].w,
                       bReg[2].x, bReg[2].y, bReg[2].z, bReg[2].w };
#pragma unroll
        for (int tri = 0; tri < 4; ++tri) {
            int b0 = by[tri * 3 + 0];
            int b1 = by[tri * 3 + 1];
            int b2 = by[tri * 3 + 2];
            bf16x8 h;
            h[0] = dec_code(b0 & 7, s);
            h[1] = dec_code((b0 >> 3) & 7, s);
            h[2] = dec_code(((b0 >> 6) & 3) | ((b1 & 1) << 2), s);
            h[3] = dec_code((b1 >> 1) & 7, s);
            h[4] = dec_code((b1 >> 4) & 7, s);
            h[5] = dec_code(((b1 >> 7) & 1) | ((b2 & 3) << 1), s);
            h[6] = dec_code((b2 >> 2) & 7, s);
            h[7] = dec_code((b2 >> 5) & 7, s);
            *(bf16x8*)(&Bs[gl][half * 32 + tri * 8]) = h;
        }
    };

    auto compute = [&]() {
#pragma unroll
        for (int ks = 0; ks < 2; ++ks) {
            bf16x8 af[4], bfr[4];
#pragma unroll
            for (int mi = 0; mi < 4; ++mi)
                af[mi] = *(const bf16x8*)(&As[wm * 64 + mi * 16 + r16][ks * 32 + quad * 8]);
#pragma unroll
            for (int ni = 0; ni < 4; ++ni)
                bfr[ni] = *(const bf16x8*)(&Bs[wn * 64 + ni * 16 + r16][ks * 32 + quad * 8]);
#pragma unroll
            for (int mi = 0; mi < 4; ++mi)
#pragma unroll
                for (int ni = 0; ni < 4; ++ni)
                    acc[mi][ni] = __builtin_amdgcn_mfma_f32_16x16x32_bf16(
                        af[mi], bfr[ni], acc[mi][ni], 0, 0, 0);
        }
    };

    loadTile(0);
    for (int kt = 0; kt < NT; ++kt) {
        __syncthreads();
        stage();
        __syncthreads();
        if (kt + 1 < NT) loadTile(kt + 1);
        compute();
    }

    const int colBase = nBase + wn * 64;
#pragma unroll
    for (int ni = 0; ni < 4; ++ni) {
        int col  = colBase + ni * 16 + r16;
        float bv = bias[col];
#pragma unroll
        for (int mi = 0; mi < 4; ++mi) {
            int row0 = mBase + wm * 64 + mi * 16 + quad * 4;
#pragma unroll
            for (int r = 0; r < 4; ++r)
                out[(size_t)(row0 + r) * N_OUT + col] = acc[mi][ni][r] + bv;
        }
    }
}

extern "C" void kernel_launch(void* const* d_in, const int* in_sizes, int n_in,
                              void* d_out, int out_size, void* d_ws, size_t ws_size,
                              hipStream_t stream) {
    const float* x      = (const float*)d_in[0];
    const int*   wq     = (const int*)d_in[1];
    const float* wscale = (const float*)d_in[2];
    const float* bias   = (const float*)d_in[3];
    float*       out    = (float*)d_out;

    const size_t wBytes  = (size_t)N_OUT * K_IN * sizeof(bf16);   // 32 MiB
    const size_t xBytes  = (size_t)M_TOK * K_IN * sizeof(bf16);   // 64 MiB

    if (ws_size >= wBytes + xBytes) {
        bf16* Wb = (bf16*)d_ws;
        bf16* Xb = (bf16*)((char*)d_ws + wBytes);
        // merged prep: 2048 dequant blocks + 16384 cvt blocks
        prep_kernel<<<2048 + 16384, 256, 0, stream>>>(wq, wscale, x, Wb, Xb);
        dim3 grid(N_OUT / 256, M_TOK / 256);   // (16, 32)
        gemm_kernel<<<grid, dim3(512), 0, stream>>>(Xb, Wb, bias, out);
    } else {
        dim3 grid(N_OUT / 128, M_TOK / 128);
        linear3bit_fused<<<grid, dim3(256), 0, stream>>>(x, wq, wscale, bias, out);
    }
}

// Round 9
// 473.640 us; speedup vs baseline: 5.7792x; 5.7792x over previous
//
#include <hip/hip_runtime.h>

#define M_TOK 8192
#define N_OUT 4096
#define K_IN  4096
#define BK    64
#define NT    (K_IN / BK)   // 64 k-tiles

typedef __bf16 bf16;
typedef bf16  bf16x4  __attribute__((ext_vector_type(4)));
typedef bf16  bf16x8  __attribute__((ext_vector_type(8)));
typedef float floatx4 __attribute__((ext_vector_type(4)));

__device__ __forceinline__ bf16 dec_code(int c, float s) {
    // clip(c-3, -3, 3) == min(c,6)-3 for c in 0..7
    int q = (c > 6 ? 6 : c) - 3;
    return (bf16)((float)q * s);
}

__device__ __forceinline__ void async_ld16(const bf16* g, const bf16* l) {
    __builtin_amdgcn_global_load_lds(
        (const __attribute__((address_space(1))) void*)g,
        (__attribute__((address_space(3))) void*)l,
        16, 0, 0);
}

// ---------------------------------------------------------------------------
// Phase 1 (merged): dequantize W -> bf16 [N][K]  AND  convert x fp32 -> bf16
//   blocks [0, 2048)          : dequant (2 threads per 64-elem group)
//   blocks [2048, 2048+16384) : x conversion (8 elems / thread)
// ---------------------------------------------------------------------------
__global__ __launch_bounds__(256)
void prep_kernel(const int* __restrict__ wq, const float* __restrict__ wscale,
                 const float* __restrict__ x,
                 bf16* __restrict__ W, bf16* __restrict__ xb)
{
    const int b = blockIdx.x;
    const int t = threadIdx.x;
    if (b < 2048) {
        int idx  = b * 256 + t;              // 0 .. 2*NUM_GROUPS-1
        int g    = idx >> 1;
        int half = idx & 1;
        const int* wp = wq + (size_t)g * 24 + half * 12;
        int4 r0 = *(const int4*)(wp);
        int4 r1 = *(const int4*)(wp + 4);
        int4 r2 = *(const int4*)(wp + 8);
        float s = wscale[g];
        int by[12] = { r0.x, r0.y, r0.z, r0.w, r1.x, r1.y, r1.z, r1.w,
                       r2.x, r2.y, r2.z, r2.w };
        bf16* dst = W + (size_t)g * 64 + half * 32;
#pragma unroll
        for (int tri = 0; tri < 4; ++tri) {
            int b0 = by[tri * 3 + 0];
            int b1 = by[tri * 3 + 1];
            int b2 = by[tri * 3 + 2];
            bf16x8 h;
            h[0] = dec_code(b0 & 7, s);
            h[1] = dec_code((b0 >> 3) & 7, s);
            h[2] = dec_code(((b0 >> 6) & 3) | ((b1 & 1) << 2), s);
            h[3] = dec_code((b1 >> 1) & 7, s);
            h[4] = dec_code((b1 >> 4) & 7, s);
            h[5] = dec_code(((b1 >> 7) & 1) | ((b2 & 3) << 1), s);
            h[6] = dec_code((b2 >> 2) & 7, s);
            h[7] = dec_code((b2 >> 5) & 7, s);
            *(bf16x8*)(dst + tri * 8) = h;
        }
    } else {
        size_t i = ((size_t)(b - 2048) * 256 + t) * 8;
        float4 a = *(const float4*)(x + i);
        float4 c = *(const float4*)(x + i + 4);
        bf16x8 h = { (bf16)a.x, (bf16)a.y, (bf16)a.z, (bf16)a.w,
                     (bf16)c.x, (bf16)c.y, (bf16)c.z, (bf16)c.w };
        *(bf16x8*)(xb + i) = h;
    }
}

// ---------------------------------------------------------------------------
// Phase 2: bf16 B^T GEMM, 256x256 tile, BK=64, 8 waves (2M x 4N), 512 thr.
//   ROUND-3 CHAMPION RESTORED EXACTLY (246 us, MfmaUtil 49.8%).
//   4-phase-per-K-tile schedule, XOR-swizzled double-buffered LDS, derived
//   counted vmcnt (never drains in steady state), natural block mapping
//   (round-5 measured: XCD override costs ~15% -- B-panel/XCD-L2 affinity).
//
// Register budget (round-8 lesson): acc = 128 AGPR + ~108 VGPR = ~236 of the
// 256 combined cap at 2 waves/SIMD.  Any >=2-waves-per-SIMD-preserving change
// must keep combined <= 256; launch_bounds(512,4) (cap 128) spills acc to
// scratch -> 11 GB HBM traffic, 10x slowdown (measured round 8).
//
// Quarter-tiles (64 rows = 1 global_load_lds per wave): AQ0..AQ3, BQ0..BQ3.
// Per-phase MFMA quadrant (16 MFMA): P0 = m0-3 x n0-1, P1 = m0-3 x n2-3,
// P2 = m4-7 x n0-1, P3 = m4-7 x n2-3 (x 2 k-slices).
// ds_reads: P0 = A(mh0) 8 + B(nj0) 4; P1 = B(nj1) 4; P2 = A(mh1) 8; P3 = 0.
// Stage plan for tile kt+1 (2 per phase, late -- measured best vs R5/R6):
//   P0 {BQ0,BQ1}, P1 {BQ2,BQ3}, P2 {AQ0,AQ2}, P3 {AQ1,AQ3}
// Per-wave FIFO waits (after MFMA, before phase-end barrier):
//   P1-end: vmcnt(4) retires prev-P3's AQ1,AQ3 (read by P2);
//   P3-end: vmcnt(2) retires BQ0-3,AQ0,AQ2 (read by next P0),
//           leaving [AQ1,AQ3] in flight -> entry invariant.
// Last tile (no stages): waits tighten to vmcnt(0) (non-vacuous).
// ---------------------------------------------------------------------------
__global__ __launch_bounds__(512, 2)
void gemm_kernel(const bf16* __restrict__ A, const bf16* __restrict__ B,
                 const float* __restrict__ bias, float* __restrict__ out)
{
    __shared__ bf16 As[2][256][BK];   // 64 KiB
    __shared__ bf16 Bs[2][256][BK];   // 64 KiB

    const int t     = threadIdx.x;
    const int nBase = blockIdx.x * 256;
    const int mBase = blockIdx.y * 256;

    const int wave = t >> 6;
    const int lane = t & 63;
    const int quad = lane >> 4;
    const int r16  = lane & 15;
    const int wm   = wave >> 2;      // 0..1  (M dim)
    const int wn   = wave & 3;       // 0..3  (N dim)
    const int sw   = r16 & 7;

    // staging: thread t covers row (t>>3) of a 64-row block, physical 16B
    // chunk (t&7); fetches logical chunk (t&7)^(row&7) so a linear
    // global_load_lds write produces the swizzled layout.
    const int rowInBlk = t >> 3;                  // 0..63
    const int lc       = (t & 7) ^ (rowInBlk & 7);

    const bf16* aSrc = A + (size_t)(mBase + rowInBlk) * K_IN + lc * 8;
    const bf16* bSrc = B + (size_t)(nBase + rowInBlk) * K_IN + lc * 8;
    bf16* aLds0 = &As[0][0][0] + t * 8;           // + buf*16384 + rowOff*64
    bf16* bLds0 = &Bs[0][0][0] + t * 8;

#define STAGE_A(KT1, BUF, ROFF) \
    async_ld16(aSrc + (size_t)(ROFF) * K_IN + (size_t)(KT1) * BK, \
               aLds0 + (BUF) * 16384 + (ROFF) * BK)
#define STAGE_B(KT1, BUF, ROFF) \
    async_ld16(bSrc + (size_t)(ROFF) * K_IN + (size_t)(KT1) * BK, \
               bLds0 + (BUF) * 16384 + (ROFF) * BK)

    floatx4 acc[8][4];
#pragma unroll
    for (int i = 0; i < 8; ++i)
#pragma unroll
        for (int j = 0; j < 4; ++j)
            acc[i][j] = (floatx4){0.f, 0.f, 0.f, 0.f};

    bf16x8 afr[2][4];   // A frags for current m-half
    bf16x8 bfr[2][4];   // B frags for whole tile (nj0 loaded P0, nj1 P1)

#define LOAD_A(CB, MH) do {                                                     \
        _Pragma("unroll") for (int ks = 0; ks < 2; ++ks)                        \
        _Pragma("unroll") for (int q = 0; q < 4; ++q)                           \
            afr[ks][q] = *(const bf16x8*)(                                      \
                &As[CB][wm * 128 + ((MH) * 4 + q) * 16 + r16]                   \
                      [((ks * 4 + quad) ^ sw) * 8]);                            \
    } while (0)
#define LOAD_B(CB, NJ) do {                                                     \
        _Pragma("unroll") for (int ks = 0; ks < 2; ++ks)                        \
        _Pragma("unroll") for (int j = 0; j < 2; ++j)                           \
            bfr[ks][(NJ) * 2 + j] = *(const bf16x8*)(                           \
                &Bs[CB][wn * 64 + ((NJ) * 2 + j) * 16 + r16]                    \
                      [((ks * 4 + quad) ^ sw) * 8]);                            \
    } while (0)

#define CLUSTER(MOFF, NOFF) do {                                                \
        __builtin_amdgcn_s_setprio(1);                                          \
        _Pragma("unroll") for (int ks = 0; ks < 2; ++ks)                        \
        _Pragma("unroll") for (int q = 0; q < 4; ++q)                           \
        _Pragma("unroll") for (int j = 0; j < 2; ++j)                           \
            acc[(MOFF) + q][(NOFF) + j] =                                       \
                __builtin_amdgcn_mfma_f32_16x16x32_bf16(                        \
                    afr[ks][q], bfr[ks][(NOFF) + j],                            \
                    acc[(MOFF) + q][(NOFF) + j], 0, 0, 0);                      \
        __builtin_amdgcn_s_setprio(0);                                          \
    } while (0)

#define PH_SYNC() do {                                                          \
        asm volatile("s_barrier\n\ts_waitcnt lgkmcnt(0)" ::: "memory");         \
        __builtin_amdgcn_sched_barrier(0);                                      \
    } while (0)
#define PH_END() asm volatile("s_barrier" ::: "memory")

    // ---- prologue: tile 0 into buf 0; FIFO [BQ0..BQ3,AQ0,AQ2,AQ1,AQ3] ----
    STAGE_B(0, 0, 0);   STAGE_B(0, 0, 64);  STAGE_B(0, 0, 128); STAGE_B(0, 0, 192);
    STAGE_A(0, 0, 0);   STAGE_A(0, 0, 128); STAGE_A(0, 0, 64);  STAGE_A(0, 0, 192);
    asm volatile("s_waitcnt vmcnt(2)" ::: "memory");   // retire all but AQ1,AQ3
    asm volatile("s_barrier" ::: "memory");

    for (int kt = 0; kt < NT; ++kt) {
        const int  cb = kt & 1;
        const int  nb = cb ^ 1;
        const bool hn = (kt + 1 < NT);

        // ---- P0 ----
        LOAD_A(cb, 0);
        LOAD_B(cb, 0);
        if (hn) { STAGE_B(kt + 1, nb, 0); STAGE_B(kt + 1, nb, 64); }
        PH_SYNC();
        CLUSTER(0, 0);
        PH_END();

        // ---- P1 ----
        LOAD_B(cb, 1);
        if (hn) { STAGE_B(kt + 1, nb, 128); STAGE_B(kt + 1, nb, 192); }
        PH_SYNC();
        CLUSTER(0, 2);
        if (hn) asm volatile("s_waitcnt vmcnt(4)" ::: "memory");
        else    asm volatile("s_waitcnt vmcnt(0)" ::: "memory");
        PH_END();   // after this barrier AQ1,AQ3 of tile kt are LDS-visible

        // ---- P2 ----
        LOAD_A(cb, 1);
        if (hn) { STAGE_A(kt + 1, nb, 0); STAGE_A(kt + 1, nb, 128); }
        PH_SYNC();
        CLUSTER(4, 0);
        PH_END();

        // ---- P3 ----
        if (hn) { STAGE_A(kt + 1, nb, 64); STAGE_A(kt + 1, nb, 192); }
        PH_SYNC();
        CLUSTER(4, 2);
        if (hn) asm volatile("s_waitcnt vmcnt(2)" ::: "memory");
        PH_END();   // next P0's ds_reads safe: BQ*,AQ0,AQ2 of kt+1 landed
    }

#undef PH_END
#undef PH_SYNC
#undef CLUSTER
#undef LOAD_B
#undef LOAD_A
#undef STAGE_A
#undef STAGE_B

    const int colBase = nBase + wn * 64;
#pragma unroll
    for (int ni = 0; ni < 4; ++ni) {
        int col  = colBase + ni * 16 + r16;
        float bv = bias[col];
#pragma unroll
        for (int mi = 0; mi < 8; ++mi) {
            int row0 = mBase + wm * 128 + mi * 16 + quad * 4;
#pragma unroll
            for (int r = 0; r < 4; ++r)
                out[(size_t)(row0 + r) * N_OUT + col] = acc[mi][ni][r] + bv;
        }
    }
}

// ---------------------------------------------------------------------------
// Fallback: proven fused kernel (round-1, passed) if ws is too small
// ---------------------------------------------------------------------------
__global__ __launch_bounds__(256, 2)
void linear3bit_fused(const float* __restrict__ x,
                      const int*   __restrict__ wq,
                      const float* __restrict__ wscale,
                      const float* __restrict__ bias,
                      float*       __restrict__ out)
{
    __shared__ bf16 As[128][BK];
    __shared__ bf16 Bs[128][BK];

    const int t     = threadIdx.x;
    const int mBase = blockIdx.y * 128;
    const int nBase = blockIdx.x * 128;

    const int wave = t >> 6;
    const int lane = t & 63;
    const int quad = lane >> 4;
    const int r16  = lane & 15;
    const int wm   = wave & 1;
    const int wn   = wave >> 1;

    floatx4 acc[4][4];
#pragma unroll
    for (int i = 0; i < 4; ++i)
#pragma unroll
        for (int j = 0; j < 4; ++j)
            acc[i][j] = (floatx4){0.f, 0.f, 0.f, 0.f};

    const int gl   = t >> 1;
    const int half = t & 1;
    const float* xBase = x + (size_t)mBase * K_IN;

    float4 aReg[8];
    int4   bReg[3];
    float  sReg;

    auto loadTile = [&](int kt) {
#pragma unroll
        for (int i = 0; i < 8; ++i) {
            int linear = i * 256 + t;
            int row    = linear >> 4;
            int c4     = (linear & 15) << 2;
            aReg[i] = *(const float4*)(xBase + (size_t)row * K_IN + kt * BK + c4);
        }
        size_t g = (size_t)(nBase + gl) * 64 + kt;
        const int* wp = wq + g * 24 + half * 12;
        bReg[0] = *(const int4*)(wp);
        bReg[1] = *(const int4*)(wp + 4);
        bReg[2] = *(const int4*)(wp + 8);
        sReg = wscale[g];
    };

    auto stage = [&]() {
#pragma unroll
        for (int i = 0; i < 8; ++i) {
            int linear = i * 256 + t;
            int row    = linear >> 4;
            int c4     = (linear & 15) << 2;
            float4 v = aReg[i];
            bf16x4 h = { (bf16)v.x, (bf16)v.y, (bf16)v.z, (bf16)v.w };
            *(bf16x4*)(&As[row][c4]) = h;
        }
        const float s = sReg;
        int by[12] = { bReg[0].x, bReg[0].y, bReg[0].z, bReg[0].w,
                       bReg[1].x, bReg[1].y, bReg[1].z, bReg[1].w,
                       bReg[2].x, bReg[2].y, bReg[2].z, bReg[2].w };
#pragma unroll
        for (int tri = 0; tri < 4; ++tri) {
            int b0 = by[tri * 3 + 0];
            int b1 = by[tri * 3 + 1];
            int b2 = by[tri * 3 + 2];
            bf16x8 h;
            h[0] = dec_code(b0 & 7, s);
            h[1] = dec_code((b0 >> 3) & 7, s);
            h[2] = dec_code(((b0 >> 6) & 3) | ((b1 & 1) << 2), s);
            h[3] = dec_code((b1 >> 1) & 7, s);
            h[4] = dec_code((b1 >> 4) & 7, s);
            h[5] = dec_code(((b1 >> 7) & 1) | ((b2 & 3) << 1), s);
            h[6] = dec_code((b2 >> 2) & 7, s);
            h[7] = dec_code((b2 >> 5) & 7, s);
            *(bf16x8*)(&Bs[gl][half * 32 + tri * 8]) = h;
        }
    };

    auto compute = [&]() {
#pragma unroll
        for (int ks = 0; ks < 2; ++ks) {
            bf16x8 af[4], bfr[4];
#pragma unroll
            for (int mi = 0; mi < 4; ++mi)
                af[mi] = *(const bf16x8*)(&As[wm * 64 + mi * 16 + r16][ks * 32 + quad * 8]);
#pragma unroll
            for (int ni = 0; ni < 4; ++ni)
                bfr[ni] = *(const bf16x8*)(&Bs[wn * 64 + ni * 16 + r16][ks * 32 + quad * 8]);
#pragma unroll
            for (int mi = 0; mi < 4; ++mi)
#pragma unroll
                for (int ni = 0; ni < 4; ++ni)
                    acc[mi][ni] = __builtin_amdgcn_mfma_f32_16x16x32_bf16(
                        af[mi], bfr[ni], acc[mi][ni], 0, 0, 0);
        }
    };

    loadTile(0);
    for (int kt = 0; kt < NT; ++kt) {
        __syncthreads();
        stage();
        __syncthreads();
        if (kt + 1 < NT) loadTile(kt + 1);
        compute();
    }

    const int colBase = nBase + wn * 64;
#pragma unroll
    for (int ni = 0; ni < 4; ++ni) {
        int col  = colBase + ni * 16 + r16;
        float bv = bias[col];
#pragma unroll
        for (int mi = 0; mi < 4; ++mi) {
            int row0 = mBase + wm * 64 + mi * 16 + quad * 4;
#pragma unroll
            for (int r = 0; r < 4; ++r)
                out[(size_t)(row0 + r) * N_OUT + col] = acc[mi][ni][r] + bv;
        }
    }
}

extern "C" void kernel_launch(void* const* d_in, const int* in_sizes, int n_in,
                              void* d_out, int out_size, void* d_ws, size_t ws_size,
                              hipStream_t stream) {
    const float* x      = (const float*)d_in[0];
    const int*   wq     = (const int*)d_in[1];
    const float* wscale = (const float*)d_in[2];
    const float* bias   = (const float*)d_in[3];
    float*       out    = (float*)d_out;

    const size_t wBytes  = (size_t)N_OUT * K_IN * sizeof(bf16);   // 32 MiB
    const size_t xBytes  = (size_t)M_TOK * K_IN * sizeof(bf16);   // 64 MiB

    if (ws_size >= wBytes + xBytes) {
        bf16* Wb = (bf16*)d_ws;
        bf16* Xb = (bf16*)((char*)d_ws + wBytes);
        // merged prep: 2048 dequant blocks + 16384 cvt blocks
        prep_kernel<<<2048 + 16384, 256, 0, stream>>>(wq, wscale, x, Wb, Xb);
        dim3 grid(N_OUT / 256, M_TOK / 256);   // (16, 32)
        gemm_kernel<<<grid, dim3(512), 0, stream>>>(Xb, Wb, bias, out);
    } else {
        dim3 grid(N_OUT / 128, M_TOK / 128);
        linear3bit_fused<<<grid, dim3(256), 0, stream>>>(x, wq, wscale, bias, out);
    }
}

// Round 10
// 466.519 us; speedup vs baseline: 5.8674x; 1.0153x over previous
//
#include <hip/hip_runtime.h>

#define M_TOK 8192
#define N_OUT 4096
#define K_IN  4096
#define BK    64
#define NT    (K_IN / BK)   // 64 k-tiles

typedef __bf16 bf16;
typedef bf16  bf16x4  __attribute__((ext_vector_type(4)));
typedef bf16  bf16x8  __attribute__((ext_vector_type(8)));
typedef float floatx4 __attribute__((ext_vector_type(4)));

__device__ __forceinline__ bf16 dec_code(int c, float s) {
    // clip(c-3, -3, 3) == min(c,6)-3 for c in 0..7
    int q = (c > 6 ? 6 : c) - 3;
    return (bf16)((float)q * s);
}

__device__ __forceinline__ void async_ld16(const bf16* g, const bf16* l) {
    __builtin_amdgcn_global_load_lds(
        (const __attribute__((address_space(1))) void*)g,
        (__attribute__((address_space(3))) void*)l,
        16, 0, 0);
}

// ---------------------------------------------------------------------------
// Phase 1 (merged, FULLY-COALESCED rewrite): dequant W -> bf16 [N][K] AND
// convert x fp32 -> bf16.
//   blocks [0, 8192)           : dequant, 32 groups/block via LDS staging
//   blocks [8192, 8192+16384)  : x conversion, 2048 floats/block
//
// Dequant coalescing: old code had each thread own a 48B input / 64B output
// chunk (1/3-1/4 lane density per instruction).  New: block loads 768 wq
// ints at stride 256 (perfectly coalesced), then thread t decodes triple
// (t&7) of group (t>>3) from LDS (addr = 3t ints -> bank 3t%32, conflict-
// free since gcd(3,32)=1) and stores ONE contiguous bf16x8 -> wave stores
// 1 KiB contiguous.  cvt: two coalesced float4 loads / bf16x4 stores.
// ---------------------------------------------------------------------------
__global__ __launch_bounds__(256)
void prep_kernel(const int* __restrict__ wq, const float* __restrict__ wscale,
                 const float* __restrict__ x,
                 bf16* __restrict__ W, bf16* __restrict__ xb)
{
    const int b = blockIdx.x;
    const int t = threadIdx.x;
    if (b < 8192) {
        __shared__ int   qbuf[768];   // 32 groups x 24 byte-values (as int32)
        __shared__ float sbuf[32];
        const int bbase = b * 32;     // first group of this block
#pragma unroll
        for (int k = 0; k < 3; ++k)
            qbuf[t + k * 256] = wq[(size_t)bbase * 24 + t + k * 256];
        if (t < 32) sbuf[t] = wscale[bbase + t];
        __syncthreads();

        const int gl = t >> 3;        // group within block (0..31)
        const int j  = t & 7;         // triple within group (0..7)
        const int b0 = qbuf[gl * 24 + j * 3 + 0];
        const int b1 = qbuf[gl * 24 + j * 3 + 1];
        const int b2 = qbuf[gl * 24 + j * 3 + 2];
        const float s = sbuf[gl];
        bf16x8 h;
        h[0] = dec_code(b0 & 7, s);
        h[1] = dec_code((b0 >> 3) & 7, s);
        h[2] = dec_code(((b0 >> 6) & 3) | ((b1 & 1) << 2), s);
        h[3] = dec_code((b1 >> 1) & 7, s);
        h[4] = dec_code((b1 >> 4) & 7, s);
        h[5] = dec_code(((b1 >> 7) & 1) | ((b2 & 3) << 1), s);
        h[6] = dec_code((b2 >> 2) & 7, s);
        h[7] = dec_code((b2 >> 5) & 7, s);
        // global addr = bbase*64 + t*8 -> 16B/lane, contiguous across wave
        *(bf16x8*)(W + (size_t)bbase * 64 + t * 8) = h;
    } else {
        const size_t base = (size_t)(b - 8192) * 2048;
        float4 a = *(const float4*)(x + base + t * 4);
        float4 c = *(const float4*)(x + base + 1024 + t * 4);
        bf16x4 ha = { (bf16)a.x, (bf16)a.y, (bf16)a.z, (bf16)a.w };
        bf16x4 hc = { (bf16)c.x, (bf16)c.y, (bf16)c.z, (bf16)c.w };
        *(bf16x4*)(xb + base + t * 4)        = ha;
        *(bf16x4*)(xb + base + 1024 + t * 4) = hc;
    }
}

// ---------------------------------------------------------------------------
// Phase 2: bf16 B^T GEMM, 256x256 tile, BK=64, 8 waves (2M x 4N), 512 thr.
//   ROUND-3 CHAMPION, UNCHANGED (round-9 control: 251 us, MfmaUtil 48.6%).
//   4-phase-per-K-tile schedule, XOR-swizzled double-buffered LDS, derived
//   counted vmcnt (never drains in steady state), natural block mapping
//   (round-5 measured: XCD override costs ~15% -- B-panel/XCD-L2 affinity).
//
// Register budget (round-8 lesson): acc = 128 AGPR + ~108 VGPR = ~236 of the
// 256 combined cap at 2 waves/SIMD; launch_bounds(512,4) spills acc ->
// 11 GB scratch traffic, 10x slowdown (measured).
//
// Quarter-tiles (64 rows = 1 global_load_lds per wave): AQ0..AQ3, BQ0..BQ3.
// Per-phase MFMA quadrant (16 MFMA): P0 = m0-3 x n0-1, P1 = m0-3 x n2-3,
// P2 = m4-7 x n0-1, P3 = m4-7 x n2-3 (x 2 k-slices).
// ds_reads: P0 = A(mh0) 8 + B(nj0) 4; P1 = B(nj1) 4; P2 = A(mh1) 8; P3 = 0.
// Stage plan for tile kt+1 (2 per phase, late -- measured best vs R5/R6):
//   P0 {BQ0,BQ1}, P1 {BQ2,BQ3}, P2 {AQ0,AQ2}, P3 {AQ1,AQ3}
// Per-wave FIFO waits (after MFMA, before phase-end barrier):
//   P1-end: vmcnt(4) retires prev-P3's AQ1,AQ3 (read by P2);
//   P3-end: vmcnt(2) retires BQ0-3,AQ0,AQ2 (read by next P0),
//           leaving [AQ1,AQ3] in flight -> entry invariant.
// Last tile (no stages): waits tighten to vmcnt(0) (non-vacuous).
// ---------------------------------------------------------------------------
__global__ __launch_bounds__(512, 2)
void gemm_kernel(const bf16* __restrict__ A, const bf16* __restrict__ B,
                 const float* __restrict__ bias, float* __restrict__ out)
{
    __shared__ bf16 As[2][256][BK];   // 64 KiB
    __shared__ bf16 Bs[2][256][BK];   // 64 KiB

    const int t     = threadIdx.x;
    const int nBase = blockIdx.x * 256;
    const int mBase = blockIdx.y * 256;

    const int wave = t >> 6;
    const int lane = t & 63;
    const int quad = lane >> 4;
    const int r16  = lane & 15;
    const int wm   = wave >> 2;      // 0..1  (M dim)
    const int wn   = wave & 3;       // 0..3  (N dim)
    const int sw   = r16 & 7;

    // staging: thread t covers row (t>>3) of a 64-row block, physical 16B
    // chunk (t&7); fetches logical chunk (t&7)^(row&7) so a linear
    // global_load_lds write produces the swizzled layout.
    const int rowInBlk = t >> 3;                  // 0..63
    const int lc       = (t & 7) ^ (rowInBlk & 7);

    const bf16* aSrc = A + (size_t)(mBase + rowInBlk) * K_IN + lc * 8;
    const bf16* bSrc = B + (size_t)(nBase + rowInBlk) * K_IN + lc * 8;
    bf16* aLds0 = &As[0][0][0] + t * 8;           // + buf*16384 + rowOff*64
    bf16* bLds0 = &Bs[0][0][0] + t * 8;

#define STAGE_A(KT1, BUF, ROFF) \
    async_ld16(aSrc + (size_t)(ROFF) * K_IN + (size_t)(KT1) * BK, \
               aLds0 + (BUF) * 16384 + (ROFF) * BK)
#define STAGE_B(KT1, BUF, ROFF) \
    async_ld16(bSrc + (size_t)(ROFF) * K_IN + (size_t)(KT1) * BK, \
               bLds0 + (BUF) * 16384 + (ROFF) * BK)

    floatx4 acc[8][4];
#pragma unroll
    for (int i = 0; i < 8; ++i)
#pragma unroll
        for (int j = 0; j < 4; ++j)
            acc[i][j] = (floatx4){0.f, 0.f, 0.f, 0.f};

    bf16x8 afr[2][4];   // A frags for current m-half
    bf16x8 bfr[2][4];   // B frags for whole tile (nj0 loaded P0, nj1 P1)

#define LOAD_A(CB, MH) do {                                                     \
        _Pragma("unroll") for (int ks = 0; ks < 2; ++ks)                        \
        _Pragma("unroll") for (int q = 0; q < 4; ++q)                           \
            afr[ks][q] = *(const bf16x8*)(                                      \
                &As[CB][wm * 128 + ((MH) * 4 + q) * 16 + r16]                   \
                      [((ks * 4 + quad) ^ sw) * 8]);                            \
    } while (0)
#define LOAD_B(CB, NJ) do {                                                     \
        _Pragma("unroll") for (int ks = 0; ks < 2; ++ks)                        \
        _Pragma("unroll") for (int j = 0; j < 2; ++j)                           \
            bfr[ks][(NJ) * 2 + j] = *(const bf16x8*)(                           \
                &Bs[CB][wn * 64 + ((NJ) * 2 + j) * 16 + r16]                    \
                      [((ks * 4 + quad) ^ sw) * 8]);                            \
    } while (0)

#define CLUSTER(MOFF, NOFF) do {                                                \
        __builtin_amdgcn_s_setprio(1);                                          \
        _Pragma("unroll") for (int ks = 0; ks < 2; ++ks)                        \
        _Pragma("unroll") for (int q = 0; q < 4; ++q)                           \
        _Pragma("unroll") for (int j = 0; j < 2; ++j)                           \
            acc[(MOFF) + q][(NOFF) + j] =                                       \
                __builtin_amdgcn_mfma_f32_16x16x32_bf16(                        \
                    afr[ks][q], bfr[ks][(NOFF) + j],                            \
                    acc[(MOFF) + q][(NOFF) + j], 0, 0, 0);                      \
        __builtin_amdgcn_s_setprio(0);                                          \
    } while (0)

#define PH_SYNC() do {                                                          \
        asm volatile("s_barrier\n\ts_waitcnt lgkmcnt(0)" ::: "memory");         \
        __builtin_amdgcn_sched_barrier(0);                                      \
    } while (0)
#define PH_END() asm volatile("s_barrier" ::: "memory")

    // ---- prologue: tile 0 into buf 0; FIFO [BQ0..BQ3,AQ0,AQ2,AQ1,AQ3] ----
    STAGE_B(0, 0, 0);   STAGE_B(0, 0, 64);  STAGE_B(0, 0, 128); STAGE_B(0, 0, 192);
    STAGE_A(0, 0, 0);   STAGE_A(0, 0, 128); STAGE_A(0, 0, 64);  STAGE_A(0, 0, 192);
    asm volatile("s_waitcnt vmcnt(2)" ::: "memory");   // retire all but AQ1,AQ3
    asm volatile("s_barrier" ::: "memory");

    for (int kt = 0; kt < NT; ++kt) {
        const int  cb = kt & 1;
        const int  nb = cb ^ 1;
        const bool hn = (kt + 1 < NT);

        // ---- P0 ----
        LOAD_A(cb, 0);
        LOAD_B(cb, 0);
        if (hn) { STAGE_B(kt + 1, nb, 0); STAGE_B(kt + 1, nb, 64); }
        PH_SYNC();
        CLUSTER(0, 0);
        PH_END();

        // ---- P1 ----
        LOAD_B(cb, 1);
        if (hn) { STAGE_B(kt + 1, nb, 128); STAGE_B(kt + 1, nb, 192); }
        PH_SYNC();
        CLUSTER(0, 2);
        if (hn) asm volatile("s_waitcnt vmcnt(4)" ::: "memory");
        else    asm volatile("s_waitcnt vmcnt(0)" ::: "memory");
        PH_END();   // after this barrier AQ1,AQ3 of tile kt are LDS-visible

        // ---- P2 ----
        LOAD_A(cb, 1);
        if (hn) { STAGE_A(kt + 1, nb, 0); STAGE_A(kt + 1, nb, 128); }
        PH_SYNC();
        CLUSTER(4, 0);
        PH_END();

        // ---- P3 ----
        if (hn) { STAGE_A(kt + 1, nb, 64); STAGE_A(kt + 1, nb, 192); }
        PH_SYNC();
        CLUSTER(4, 2);
        if (hn) asm volatile("s_waitcnt vmcnt(2)" ::: "memory");
        PH_END();   // next P0's ds_reads safe: BQ*,AQ0,AQ2 of kt+1 landed
    }

#undef PH_END
#undef PH_SYNC
#undef CLUSTER
#undef LOAD_B
#undef LOAD_A
#undef STAGE_A
#undef STAGE_B

    const int colBase = nBase + wn * 64;
#pragma unroll
    for (int ni = 0; ni < 4; ++ni) {
        int col  = colBase + ni * 16 + r16;
        float bv = bias[col];
#pragma unroll
        for (int mi = 0; mi < 8; ++mi) {
            int row0 = mBase + wm * 128 + mi * 16 + quad * 4;
#pragma unroll
            for (int r = 0; r < 4; ++r)
                out[(size_t)(row0 + r) * N_OUT + col] = acc[mi][ni][r] + bv;
        }
    }
}

// ---------------------------------------------------------------------------
// Fallback: proven fused kernel (round-1, passed) if ws is too small
// ---------------------------------------------------------------------------
__global__ __launch_bounds__(256, 2)
void linear3bit_fused(const float* __restrict__ x,
                      const int*   __restrict__ wq,
                      const float* __restrict__ wscale,
                      const float* __restrict__ bias,
                      float*       __restrict__ out)
{
    __shared__ bf16 As[128][BK];
    __shared__ bf16 Bs[128][BK];

    const int t     = threadIdx.x;
    const int mBase = blockIdx.y * 128;
    const int nBase = blockIdx.x * 128;

    const int wave = t >> 6;
    const int lane = t & 63;
    const int quad = lane >> 4;
    const int r16  = lane & 15;
    const int wm   = wave & 1;
    const int wn   = wave >> 1;

    floatx4 acc[4][4];
#pragma unroll
    for (int i = 0; i < 4; ++i)
#pragma unroll
        for (int j = 0; j < 4; ++j)
            acc[i][j] = (floatx4){0.f, 0.f, 0.f, 0.f};

    const int gl   = t >> 1;
    const int half = t & 1;
    const float* xBase = x + (size_t)mBase * K_IN;

    float4 aReg[8];
    int4   bReg[3];
    float  sReg;

    auto loadTile = [&](int kt) {
#pragma unroll
        for (int i = 0; i < 8; ++i) {
            int linear = i * 256 + t;
            int row    = linear >> 4;
            int c4     = (linear & 15) << 2;
            aReg[i] = *(const float4*)(xBase + (size_t)row * K_IN + kt * BK + c4);
        }
        size_t g = (size_t)(nBase + gl) * 64 + kt;
        const int* wp = wq + g * 24 + half * 12;
        bReg[0] = *(const int4*)(wp);
        bReg[1] = *(const int4*)(wp + 4);
        bReg[2] = *(const int4*)(wp + 8);
        sReg = wscale[g];
    };

    auto stage = [&]() {
#pragma unroll
        for (int i = 0; i < 8; ++i) {
            int linear = i * 256 + t;
            int row    = linear >> 4;
            int c4     = (linear & 15) << 2;
            float4 v = aReg[i];
            bf16x4 h = { (bf16)v.x, (bf16)v.y, (bf16)v.z, (bf16)v.w };
            *(bf16x4*)(&As[row][c4]) = h;
        }
        const float s = sReg;
        int by[12] = { bReg[0].x, bReg[0].y, bReg[0].z, bReg[0].w,
                       bReg[1].x, bReg[1].y, bReg[1].z, bReg[1].w,
                       bReg[2].x, bReg[2].y, bReg[2].z, bReg[2].w };
#pragma unroll
        for (int tri = 0; tri < 4; ++tri) {
            int b0 = by[tri * 3 + 0];
            int b1 = by[tri * 3 + 1];
            int b2 = by[tri * 3 + 2];
            bf16x8 h;
            h[0] = dec_code(b0 & 7, s);
            h[1] = dec_code((b0 >> 3) & 7, s);
            h[2] = dec_code(((b0 >> 6) & 3) | ((b1 & 1) << 2), s);
            h[3] = dec_code((b1 >> 1) & 7, s);
            h[4] = dec_code((b1 >> 4) & 7, s);
            h[5] = dec_code(((b1 >> 7) & 1) | ((b2 & 3) << 1), s);
            h[6] = dec_code((b2 >> 2) & 7, s);
            h[7] = dec_code((b2 >> 5) & 7, s);
            *(bf16x8*)(&Bs[gl][half * 32 + tri * 8]) = h;
        }
    };

    auto compute = [&]() {
#pragma unroll
        for (int ks = 0; ks < 2; ++ks) {
            bf16x8 af[4], bfr[4];
#pragma unroll
            for (int mi = 0; mi < 4; ++mi)
                af[mi] = *(const bf16x8*)(&As[wm * 64 + mi * 16 + r16][ks * 32 + quad * 8]);
#pragma unroll
            for (int ni = 0; ni < 4; ++ni)
                bfr[ni] = *(const bf16x8*)(&Bs[wn * 64 + ni * 16 + r16][ks * 32 + quad * 8]);
#pragma unroll
            for (int mi = 0; mi < 4; ++mi)
#pragma unroll
                for (int ni = 0; ni < 4; ++ni)
                    acc[mi][ni] = __builtin_amdgcn_mfma_f32_16x16x32_bf16(
                        af[mi], bfr[ni], acc[mi][ni], 0, 0, 0);
        }
    };

    loadTile(0);
    for (int kt = 0; kt < NT; ++kt) {
        __syncthreads();
        stage();
        __syncthreads();
        if (kt + 1 < NT) loadTile(kt + 1);
        compute();
    }

    const int colBase = nBase + wn * 64;
#pragma unroll
    for (int ni = 0; ni < 4; ++ni) {
        int col  = colBase + ni * 16 + r16;
        float bv = bias[col];
#pragma unroll
        for (int mi = 0; mi < 4; ++mi) {
            int row0 = mBase + wm * 64 + mi * 16 + quad * 4;
#pragma unroll
            for (int r = 0; r < 4; ++r)
                out[(size_t)(row0 + r) * N_OUT + col] = acc[mi][ni][r] + bv;
        }
    }
}

extern "C" void kernel_launch(void* const* d_in, const int* in_sizes, int n_in,
                              void* d_out, int out_size, void* d_ws, size_t ws_size,
                              hipStream_t stream) {
    const float* x      = (const float*)d_in[0];
    const int*   wq     = (const int*)d_in[1];
    const float* wscale = (const float*)d_in[2];
    const float* bias   = (const float*)d_in[3];
    float*       out    = (float*)d_out;

    const size_t wBytes  = (size_t)N_OUT * K_IN * sizeof(bf16);   // 32 MiB
    const size_t xBytes  = (size_t)M_TOK * K_IN * sizeof(bf16);   // 64 MiB

    if (ws_size >= wBytes + xBytes) {
        bf16* Wb = (bf16*)d_ws;
        bf16* Xb = (bf16*)((char*)d_ws + wBytes);
        // merged prep: 8192 dequant blocks + 16384 cvt blocks, all coalesced
        prep_kernel<<<8192 + 16384, 256, 0, stream>>>(wq, wscale, x, Wb, Xb);
        dim3 grid(N_OUT / 256, M_TOK / 256);   // (16, 32)
        gemm_kernel<<<grid, dim3(512), 0, stream>>>(Xb, Wb, bias, out);
    } else {
        dim3 grid(N_OUT / 128, M_TOK / 128);
        linear3bit_fused<<<grid, dim3(256), 0, stream>>>(x, wq, wscale, bias, out);
    }
}